// Round 2
// baseline (1367.748 us; speedup 1.0000x reference)
//
#include <hip/hip_runtime.h>
#include <cstdint>

#define H       192
#define TWOH    384
#define PATCHES 64
#define RADIUS  0.42f
#define BSCALE  0.18f
#define NEGINF  -1e9f
#define MT      128

// Bijective swizzled address for the 128x128 logits/weights overlay (64 KB).
// cp = col ^ ((row>>3)&3); addr = cp*128 + ((row+cp)&127).
__device__ __forceinline__ int lsAddr(int col, int row) {
  int cp = col ^ ((row >> 3) & 3);
  return (cp << 7) + ((row + cp) & 127);
}

__global__ __launch_bounds__(256, 2)
void taps_fused_kernel(const float* __restrict__ tok, const float* __restrict__ prv,
                       const float* __restrict__ Wsel, const float* __restrict__ bsel,
                       const float* __restrict__ Wbr,  const float* __restrict__ bbr,
                       const float* __restrict__ pv,   const float* __restrict__ pp,
                       float* __restrict__ out, int B) {
  __shared__ float smem[16384];            // logits/weights overlay only
  const int t = threadIdx.x;
  const int row0 = blockIdx.x * MT;
  const int tr = t >> 4, tc = t & 15;
  const int r0 = tr << 3, c0 = tc << 3;

  const size_t oW = (size_t)B * 192, oA = (size_t)B * 256, oLM = (size_t)B * 259,
               oBM = (size_t)B * 260, oMD = (size_t)B * 261, oR = (size_t)B * 262,
               oS = (size_t)B * 263;

  // ---- Phase 1: logits[128][128] = [tok|prv] @ Wcat^T, LDS-free, reg dbuf ----
  uint32_t rA[8];
#pragma unroll
  for (int i = 0; i < 8; i++) {
    int gr = row0 + r0 + i; if (gr >= B) gr = B - 1;
    rA[i] = (uint32_t)gr * H;
  }
  const float* wB = (c0 < PATCHES) ? (Wsel + (size_t)c0 * TWOH)
                                   : (Wbr + (size_t)(c0 - PATCHES) * TWOH);

  float acc[8][8];
#pragma unroll
  for (int i = 0; i < 8; i++)
#pragma unroll
    for (int j = 0; j < 8; j++) acc[i][j] = 0.f;

  float4 aX[8], bX[8], aY[8], bY[8];

#define LOADA(DST, SRC, KK)                                              \
  { _Pragma("unroll") for (int i_ = 0; i_ < 8; i_++)                     \
      DST[i_] = *(const float4*)((SRC) + rA[i_] + (KK)); }
#define LOADW(DST, KK)                                                   \
  { _Pragma("unroll") for (int j_ = 0; j_ < 8; j_++)                     \
      DST[j_] = *(const float4*)(wB + (size_t)j_ * TWOH + (KK)); }
#define FMAC(AA, BB, C)                                                  \
  { _Pragma("unroll") for (int i_ = 0; i_ < 8; i_++) {                   \
      const float av_ = AA[i_].C;                                        \
      _Pragma("unroll") for (int j_ = 0; j_ < 8; j_++)                   \
        acc[i_][j_] = fmaf(av_, BB[j_].C, acc[i_][j_]); } }
#define FMA4(AA, BB) FMAC(AA, BB, x) FMAC(AA, BB, y) FMAC(AA, BB, z) FMAC(AA, BB, w)

  LOADA(aX, tok, 0)
  LOADW(bX, 0)
#pragma unroll 1
  for (int wn = 0; wn < 96; wn += 2) {
    {
      const int n1 = wn + 1;
      const float* s1 = (n1 < 48) ? tok : prv;
      const int k1 = (n1 < 48) ? (n1 << 2) : ((n1 - 48) << 2);
      LOADA(aY, s1, k1)
      LOADW(bY, n1 << 2)
      FMA4(aX, bX)
    }
    {
      const int n2 = (wn + 2 < 96) ? wn + 2 : 95;   // last prefetch harmless dup
      const float* s2 = (n2 < 48) ? tok : prv;
      const int k2 = (n2 < 48) ? (n2 << 2) : ((n2 - 48) << 2);
      LOADA(aX, s2, k2)
      LOADW(bX, n2 << 2)
      FMA4(aY, bY)
    }
  }

  // bias + park logits (wave-local: wave w writes rows 32w..32w+31)
  {
    float bias[8];
#pragma unroll
    for (int j = 0; j < 8; j++) {
      int n = c0 + j;
      bias[j] = (n < PATCHES) ? bsel[n] : bbr[n - PATCHES];
    }
#pragma unroll
    for (int i = 0; i < 8; i++)
#pragma unroll
      for (int j = 0; j < 8; j++)
        smem[lsAddr(c0 + j, r0 + i)] = acc[i][j] + bias[j];
  }
  // no __syncthreads: phase 3 is wave-local on the same 32-row band

  // ---- Phase 3: per-row postprocess, 2 lanes per row ----
  {
    const int lane = t & 63;
    const int wv = t >> 6;
    const int h = lane >> 5;
    const int rl = lane & 31;
    const int row = (wv << 5) + rl;
    const int rowg = row0 + row;
    const bool valid = rowg < B;
    const int kb0 = h << 5;
    const int swz = (row >> 3) & 3;

    const float lc0 = pp[0], lc1 = pp[48], lc2 = pp[96], lc3 = pp[144];
    const float pxA = h ? lc2 : lc0;
    const float pxB = h ? lc3 : lc1;
#define CSEL(q) ((q) == 0 ? lc0 : (q) == 1 ? lc1 : (q) == 2 ? lc2 : lc3)

    float da[32], bl[32];

    // pass 1: max over sel logits (permuted col order is fine for max)
    float mxv = -3.0e38f;
#pragma unroll
    for (int j = 0; j < 32; j++) {
      int cp = kb0 + j;
      mxv = fmaxf(mxv, smem[(cp << 7) + ((row + cp) & 127)]);
    }
    mxv = fmaxf(mxv, __shfl_xor(mxv, 32, 64));

    // pass 2: exp-sum + anchor accumulation (coords from idx = j^swz)
    float ssum = 0.f, apx = 0.f, apy = 0.f, apz = 0.f;
#pragma unroll
    for (int j = 0; j < 32; j++) {
      int cp = kb0 + j;
      float v = smem[(cp << 7) + ((row + cp) & 127)];
      float e = __expf(v - mxv);
      ssum += e;
      int idx = j ^ swz;
      float px = ((idx >> 4) == 0) ? pxA : pxB;
      float py = CSEL((idx >> 2) & 3);
      float pz = CSEL(idx & 3);
      apx = fmaf(e, px, apx);
      apy = fmaf(e, py, apy);
      apz = fmaf(e, pz, apz);
    }
    ssum += __shfl_xor(ssum, 32, 64);
    apx  += __shfl_xor(apx, 32, 64);
    apy  += __shfl_xor(apy, 32, 64);
    apz  += __shfl_xor(apz, 32, 64);
    const float inv_s = 1.0f / ssum;
    const float ax = apx * inv_s, ay = apy * inv_s, az = apz * inv_s;

    // pass 3: distances + argmin (natural order, first-index tie-break)
    float dmin = 3.0e38f; int nmin = PATCHES;
#pragma unroll
    for (int i = 0; i < 32; i++) {
      float px = (i < 16) ? pxA : pxB;
      float py = CSEL((i >> 2) & 3);
      float pz = CSEL(i & 3);
      float dx = ax - px, dy = ay - py, dz = az - pz;
      float d = sqrtf(fmaf(dx, dx, fmaf(dy, dy, dz * dz)));
      da[i] = d;
      if (d < dmin) { dmin = d; nmin = kb0 + i; }
    }
    {
      float od = __shfl_xor(dmin, 32, 64);
      int   oi = __shfl_xor(nmin, 32, 64);
      if (od < dmin || (od == dmin && oi < nmin)) { dmin = od; nmin = oi; }
    }

    // pass 4: masked bridge logits -> bl[], per-half sorted top-6 insertion
    float q0 = -3.0e38f, q1 = -3.0e38f, q2 = -3.0e38f,
          q3 = -3.0e38f, q4 = -3.0e38f, q5 = -3.0e38f;
#pragma unroll
    for (int i = 0; i < 32; i++) {
      int c = ((kb0 + i) ^ swz) + 64;
      float v = smem[(c << 7) + ((row + c) & 127)];
      bool loc = (da[i] <= RADIUS) || (kb0 + i == nmin);
      v = loc ? NEGINF : v;
      bl[i] = v;
      float cur = v, n_;
      n_ = fmaxf(q0, cur); cur = fminf(q0, cur); q0 = n_;
      n_ = fmaxf(q1, cur); cur = fminf(q1, cur); q1 = n_;
      n_ = fmaxf(q2, cur); cur = fminf(q2, cur); q2 = n_;
      n_ = fmaxf(q3, cur); cur = fminf(q3, cur); q3 = n_;
      n_ = fmaxf(q4, cur); cur = fminf(q4, cur); q4 = n_;
      q5 = fmaxf(q5, cur);
    }
    // merge the two sorted-6 lists
    const float o0 = __shfl_xor(q0, 32, 64), o1 = __shfl_xor(q1, 32, 64),
                o2 = __shfl_xor(q2, 32, 64), o3 = __shfl_xor(q3, 32, 64),
                o4 = __shfl_xor(q4, 32, 64), o5 = __shfl_xor(q5, 32, 64);
    const float v0 = fmaxf(q0, o0);
    const float v1 = fmaxf(fmaxf(q1, o1), fminf(q0, o0));
    const float v2 = fmaxf(fmaxf(q2, o2), fmaxf(fminf(q0, o1), fminf(q1, o0)));
    const float v3 = fmaxf(fmaxf(q3, o3),
                     fmaxf(fmaxf(fminf(q0, o2), fminf(q1, o1)), fminf(q2, o0)));
    const float v4 = fmaxf(fmaxf(q4, o4),
                     fmaxf(fmaxf(fminf(q0, o3), fminf(q1, o2)),
                           fmaxf(fminf(q2, o1), fminf(q3, o0))));
    const float v5 = fmaxf(fmaxf(q5, o5),
                     fmaxf(fmaxf(fminf(q0, o4), fminf(q1, o3)),
                           fmaxf(fminf(q2, o2),
                                 fmaxf(fminf(q3, o1), fminf(q4, o0)))));
    const float m6 = v0;
    const float esum = 1.0f + __expf(v1 - m6) + __expf(v2 - m6) +
                       __expf(v3 - m6) + __expf(v4 - m6) + __expf(v5 - m6);
    const float inv_e = 1.0f / esum;
    const float thr = v5;
    const int ngTot = (v0 > thr) + (v1 > thr) + (v2 > thr) + (v3 > thr) + (v4 > thr);
    const int eqTake = 6 - ngTot;

    int ne = 0;
#pragma unroll
    for (int i = 0; i < 32; i++) ne += (bl[i] == thr) ? 1 : 0;
    const int neOth = __shfl_xor(ne, 32, 64);
    const int eqStart = h ? neOth : 0;

    // pass 6: mixed weights (bw recomputed from parked sel logits)
    const float KLK = -1.0f / (2.0f * RADIUS * RADIUS);
    float msum = 0.f;
    unsigned int locBits = 0u;
    int eqc = 0;
#pragma unroll
    for (int i = 0; i < 32; i++) {
      float v = bl[i];
      bool loc = (v == NEGINF);
      int c = (kb0 + i) ^ swz;
      float selLog = smem[(c << 7) + ((row + c) & 127)];
      float bw = __expf(selLog - mxv) * inv_s;
      float lk = __expf(da[i] * da[i] * KLK);
      bool iseq = (v == thr);
      bool sel = (v > thr) || (iseq && ((eqStart + eqc) < eqTake));
      eqc += iseq ? 1 : 0;
      float sb = sel ? __expf(v - m6) * inv_e : 0.f;
      float mixed = loc ? (bw * lk) : (BSCALE * sb);
      bl[i] = mixed;
      msum += mixed;
      if (loc) locBits |= (1u << i);
    }
    msum += __shfl_xor(msum, 32, 64);
    const float rinv = 1.0f / fmaxf(msum, 1e-6f);

    // pass 7: normalize, masses, park weights
    float lmass = 0.f, bmass = 0.f, md = 0.f;
#pragma unroll
    for (int i = 0; i < 32; i++) {
      float w = bl[i] * rinv;
      if ((locBits >> i) & 1u) lmass += w; else bmass += w;
      md = fmaf(w, da[i], md);
      int c = (kb0 + i) ^ swz;
      smem[(c << 7) + ((row + c) & 127)] = w;
    }
    lmass += __shfl_xor(lmass, 32, 64);
    bmass += __shfl_xor(bmass, 32, 64);
    md    += __shfl_xor(md, 32, 64);

    if (valid && h == 0) {
      out[oA + (size_t)rowg * 3 + 0] = ax;
      out[oA + (size_t)rowg * 3 + 1] = ay;
      out[oA + (size_t)rowg * 3 + 2] = az;
      out[oLM + rowg] = lmass;
      out[oBM + rowg] = bmass;
      out[oMD + rowg] = md;
      out[oR  + rowg] = RADIUS;
      out[oS  + rowg] = BSCALE;
    }
#undef CSEL
  }
  __syncthreads();

  // coalesced weights store: 8 float4 per thread
#pragma unroll
  for (int q = 0; q < 8; q++) {
    int slot = t + (q << 8);
    int r = slot >> 4;
    int c4 = (slot & 15) << 2;
    int rg = row0 + r;
    if (rg < B) {
      float4 w4;
      w4.x = smem[lsAddr(c4 + 0, r)];
      w4.y = smem[lsAddr(c4 + 1, r)];
      w4.z = smem[lsAddr(c4 + 2, r)];
      w4.w = smem[lsAddr(c4 + 3, r)];
      *(float4*)(out + oW + (size_t)rg * 64 + c4) = w4;
    }
  }

  // ---- Phase 4: patch_state[128][192] = Ws[128][64] @ pv[64][192] ----
  {
    const int c0b = tc * 12;
    const int swz4 = tr & 3;                 // ((r0+i)>>3)&3 for i<8
    float acc2[8][12];
#pragma unroll
    for (int i = 0; i < 8; i++)
#pragma unroll
      for (int j = 0; j < 12; j++) acc2[i][j] = 0.f;

#pragma unroll 2
    for (int k = 0; k < PATCHES; k++) {
      int c = k ^ swz4;
      const float* wrow = smem + (c << 7);
      int rb = r0 + c;
      float wk[8];
#pragma unroll
      for (int i = 0; i < 8; i++) wk[i] = wrow[(rb + i) & 127];
      float4 p0 = *(const float4*)(pv + k * H + c0b);
      float4 p1 = *(const float4*)(pv + k * H + c0b + 4);
      float4 p2 = *(const float4*)(pv + k * H + c0b + 8);
      float pvv[12] = {p0.x, p0.y, p0.z, p0.w, p1.x, p1.y, p1.z, p1.w,
                       p2.x, p2.y, p2.z, p2.w};
#pragma unroll
      for (int i = 0; i < 8; i++)
#pragma unroll
        for (int j = 0; j < 12; j++)
          acc2[i][j] = fmaf(wk[i], pvv[j], acc2[i][j]);
    }
#pragma unroll
    for (int i = 0; i < 8; i++) {
      int rg = row0 + r0 + i;
      if (rg < B) {
        float* o = out + (size_t)rg * H + c0b;
        *(float4*)(o + 0) = make_float4(acc2[i][0], acc2[i][1], acc2[i][2], acc2[i][3]);
        *(float4*)(o + 4) = make_float4(acc2[i][4], acc2[i][5], acc2[i][6], acc2[i][7]);
        *(float4*)(o + 8) = make_float4(acc2[i][8], acc2[i][9], acc2[i][10], acc2[i][11]);
      }
    }
  }
}

extern "C" void kernel_launch(void* const* d_in, const int* in_sizes, int n_in,
                              void* d_out, int out_size, void* d_ws, size_t ws_size,
                              hipStream_t stream) {
  const float* tok  = (const float*)d_in[0];
  const float* prv  = (const float*)d_in[1];
  const float* Wsel = (const float*)d_in[2];
  const float* bsel = (const float*)d_in[3];
  const float* Wbr  = (const float*)d_in[4];
  const float* bbr  = (const float*)d_in[5];
  const float* pv   = (const float*)d_in[6];
  const float* pp   = (const float*)d_in[7];
  float* out = (float*)d_out;
  const int B = in_sizes[0] / H;
  const int grid = (B + MT - 1) / MT;
  hipLaunchKernelGGL(taps_fused_kernel, dim3(grid), dim3(256), 0, stream,
                     tok, prv, Wsel, bsel, Wbr, bbr, pv, pp, out, B);
}